// Round 13
// baseline (121.245 us; speedup 1.0000x reference)
//
#include <hip/hip_runtime.h>
#include <hip/hip_bf16.h>

// Problem constants
#define NB   32      // batch
#define NC   24      // image channels
#define ND   12      // spatial
#define NN   144     // ND*ND objects
#define QD   11
#define GH   256
#define FOUT 10

typedef unsigned short u16;
typedef __attribute__((ext_vector_type(8))) short bf16x8;
typedef __attribute__((ext_vector_type(4))) float f32x4;

// Workspace layout (u16 units unless noted):
//   Lqb  u16 [32][144][256]  off 0          (= L + q@Wg1_q + bg1, bf16)
//   Rb   u16 [32][144][256]  off 1179648
//   Bswz u16 [128][64][8]    off 2359296    (MFMA B-fragment order)
//   S    f32 [32][256]       byte-off 4849664
#define LQ_U16  0
#define R_U16   1179648
#define BS_U16  2359296
#define S_BYTE  4849664

__device__ inline float b2f(u16 v) {
  union { unsigned u; float f; } c; c.u = ((unsigned)v) << 16; return c.f;
}
__device__ inline u16 f2b(float f) {
  __hip_bfloat16 h = __float2bfloat16(f);
  return *reinterpret_cast<u16*>(&h);
}

// ---------------------------------------------------------------------------
// Fused prep:
//  blocks [0, 9216): per-object projections -> bf16 (Lq folds q-term + bg1).
//  blocks [9216, 9472): Wg2 -> bf16 B-fragment swizzle; zero S.
// ---------------------------------------------------------------------------
__global__ __launch_bounds__(256) void prep(const float* __restrict__ image,
                                            const float* __restrict__ question,
                                            const float* __restrict__ Wg1,
                                            const float* __restrict__ bg1,
                                            const float* __restrict__ Wg2,
                                            u16* __restrict__ Lq,
                                            u16* __restrict__ R,
                                            float* __restrict__ S,
                                            u16* __restrict__ Bswz) {
  int blk = blockIdx.x;
  int h   = threadIdx.x;
  if (blk < 2 * NB * NN) {
    int p     = blk % NN;
    int rest2 = blk / NN;
    int b     = rest2 & (NB - 1);
    int which = rest2 >> 5;
    const float* Wrow = Wg1 + which * (NC + 2) * GH;
    const float* img  = image + b * (NC * NN) + p;
    float acc = 0.f;
#pragma unroll
    for (int c = 0; c < NC; ++c) acc += img[c * NN] * Wrow[c * GH + h];
    int i = p / ND, j = p - i * ND;
    const float inv = 1.0f / (ND - 1);
    acc += (j * inv) * Wrow[24 * GH + h];
    acc += (i * inv) * Wrow[25 * GH + h];
    if (which == 0) {
      acc += bg1[h];
#pragma unroll
      for (int tq = 0; tq < QD; ++tq)
        acc += question[b * QD + tq] * Wg1[(2 * (NC + 2) + tq) * GH + h];
      Lq[(b * NN + p) * GH + h] = f2b(acc);
    } else {
      R[(b * NN + p) * GH + h] = f2b(acc);
    }
  } else {
    int tid = (blk - 2 * NB * NN) * 256 + h;   // 0..65535
    int e   = tid & 7;
    int l   = (tid >> 3) & 63;
    int fid = tid >> 9;
    int kt  = fid >> 4, nt = fid & 15;
    int k = kt * 32 + ((l >> 4) << 3) + e;
    int n = (nt << 4) + (l & 15);
    Bswz[tid] = f2b(Wg2[k * GH + n]);
    if (tid < NB * GH) S[tid] = 0.f;
  }
}

// ---------------------------------------------------------------------------
// MFMA pair GEMM v13. Block = 512 thr (8 waves, wave-grid 2m x 4n), tile =
// 128 pairs x 256 cols, LDS DOUBLE-buffered (2 x 64 KB = 128 KB, 1 block/CU).
// Per tile ONE barrier: MFMA(t) reads buf[cur] while build(t+1) writes
// buf[cur^1] (no intra-tile dependence). Wave-parity stagger: even waves
// {build; MFMA}, odd waves {MFMA; build} -> per SIMD the 2 resident waves
// run in anti-phase, so build VALU hides under the other wave's MFMA stream.
// Registers proven to fit (v12); bounds (512,1) -> cap 256, no spill risk.
// Grid = 256 blocks (1/CU) XCD-pinned; ~20 tiles/block.
// ---------------------------------------------------------------------------
__global__ __launch_bounds__(512, 1) void pair_gemm(const u16* __restrict__ Lq,
                                                    const u16* __restrict__ R,
                                                    const u16* __restrict__ Bswz,
                                                    const float* __restrict__ bg2,
                                                    float* __restrict__ S) {
  const int bid = blockIdx.x;          // 0..255
  const int xcd = bid & 7;
  const int idx = bid >> 3;            // 0..31
  const int b   = xcd * 4 + (idx >> 3);
  const int bi  = idx & 7;             // 8 blocks per batch, 162 tiles
  const int t0  = bi * 20 + (bi < 2 ? bi : 2);
  const int cnt = 20 + (bi < 2 ? 1 : 0);

  // [buf 2][kt 8][mf 8][lane 64][8 bf16] = 128 KB
  __shared__ __align__(16) u16 As[2][32768];

  const int t = threadIdx.x;
  const int w = t >> 6, l = t & 63;
  const int wn = w & 3, wm = w >> 2;
  // builder role: row t>>2 (0..127), k-octet t&3
  const int brow = t >> 2;
  const int oc   = t & 3;
  const int mf_w   = brow >> 4;                              // 0..7
  const int lane_w = ((brow & 15) | (oc << 4)) ^ (oc << 1);  // 2-way (free)
  const int lane_r = l ^ (((l >> 4) & 3) << 1);

  const u16* Lbase = Lq + b * NN * GH;
  const u16* Rbase = R + b * NN * GH;
  const u16* Bl    = Bswz + l * 8;

  float bgv[4];
#pragma unroll
  for (int nt = 0; nt < 4; ++nt)
    bgv[nt] = bg2[(wn << 6) + (nt << 4) + (l & 15)];
  float ssum[4] = {0.f, 0.f, 0.f, 0.f};

  // ---- build helper: tile tg -> dst (fragment layout, swizzled lanes) ----
  auto build_tile = [&](int tg, u16* dst) {
    int p = tg * 128 + brow;
    int i = p / NN, j = p - i * NN;
    const u16* Lr = Lbase + i * GH + oc * 8;
    const u16* Rr = Rbase + j * GH + oc * 8;
#pragma unroll
    for (int half = 0; half < 2; ++half) {
      bf16x8 lv[4], rv[4];
#pragma unroll
      for (int q = 0; q < 4; ++q) {
        lv[q] = *(const bf16x8*)(Lr + ((half << 2) | q) * 32);
        rv[q] = *(const bf16x8*)(Rr + ((half << 2) | q) * 32);
      }
#pragma unroll
      for (int q = 0; q < 4; ++q) {
        const int kt = (half << 2) | q;
        u16 o[8];
#pragma unroll
        for (int e = 0; e < 8; ++e) {
          float v = b2f((u16)lv[q][e]) + b2f((u16)rv[q][e]);
          o[e] = f2b(v > 0.f ? v : 0.f);
        }
        *(bf16x8*)&dst[((((kt << 3) | mf_w) << 6) | lane_w) << 3] = *(bf16x8*)o;
      }
    }
  };

  // Prologue: build tile t0 into As[0]
  build_tile(t0, &As[0][0]);
  __syncthreads();

  int cur = 0;
  for (int tt = 0; tt < cnt; ++tt) {
    const bool hb = (tt + 1 < cnt);
    f32x4 acc[4][4] = {};
    const u16* src = &As[cur][0];
    u16*       dst = &As[cur ^ 1][0];

    auto do_mma = [&]() {
#pragma unroll
      for (int kt = 0; kt < 8; ++kt) {
        bf16x8 af[4];
#pragma unroll
        for (int mf = 0; mf < 4; ++mf)
          af[mf] = *(const bf16x8*)
              &src[((((kt << 3) | (wm << 2) | mf) << 6) | lane_r) << 3];
        bf16x8 bfr[4];
#pragma unroll
        for (int nt = 0; nt < 4; ++nt) {
          int fid = (kt << 4) | (wn << 2) | nt;
          bfr[nt] = *(const bf16x8*)(Bl + ((size_t)fid << 9));
        }
        __builtin_amdgcn_s_setprio(1);
#pragma unroll
        for (int mf = 0; mf < 4; ++mf)
#pragma unroll
          for (int nt = 0; nt < 4; ++nt)
            acc[mf][nt] = __builtin_amdgcn_mfma_f32_16x16x32_bf16(
                af[mf], bfr[nt], acc[mf][nt], 0, 0, 0);
        __builtin_amdgcn_s_setprio(0);
      }
    };

    // anti-phase: even waves build first, odd waves MFMA first
    if (w & 1) {
      do_mma();
      if (hb) build_tile(t0 + tt + 1, dst);
    } else {
      if (hb) build_tile(t0 + tt + 1, dst);
      do_mma();
    }

    // epilogue: fold relu(acc + bg2) into running sums
#pragma unroll
    for (int nt = 0; nt < 4; ++nt) {
      float s = 0.f;
#pragma unroll
      for (int mf = 0; mf < 4; ++mf)
#pragma unroll
        for (int r = 0; r < 4; ++r) {
          float v = acc[mf][nt][r] + bgv[nt];
          s += v > 0.f ? v : 0.f;
        }
      ssum[nt] += s;
    }
    __syncthreads();
    cur ^= 1;
  }

  // Final reduce: C/D col = l&15; shfl-reduce rows, one atomic per col slice
  float* Sb = S + b * GH;
#pragma unroll
  for (int nt = 0; nt < 4; ++nt) {
    float s = ssum[nt];
    s += __shfl_xor(s, 16, 64);
    s += __shfl_xor(s, 32, 64);
    if (l < 16) atomicAdd(&Sb[(wn << 6) + (nt << 4) + l], s);
  }
}

// ---------------------------------------------------------------------------
// Final f-MLP: out = relu(S@Wf1+bf1)@Wf2+bf2. One block per batch.
// ---------------------------------------------------------------------------
__global__ __launch_bounds__(256) void final_mlp(const float* __restrict__ S,
                                                 const float* __restrict__ Wf1,
                                                 const float* __restrict__ bf1,
                                                 const float* __restrict__ Wf2,
                                                 const float* __restrict__ bf2,
                                                 float* __restrict__ out) {
  __shared__ float sS[GH];
  __shared__ float oS[GH];
  int b = blockIdx.x, h = threadIdx.x;
  sS[h] = S[b * GH + h];
  __syncthreads();
  float acc = bf1[h];
#pragma unroll 8
  for (int k = 0; k < GH; ++k) acc += sS[k] * Wf1[k * GH + h];
  oS[h] = acc > 0.f ? acc : 0.f;
  __syncthreads();
  if (h < FOUT) {
    float o = bf2[h];
#pragma unroll 8
    for (int k = 0; k < GH; ++k) o += oS[k] * Wf2[k * FOUT + h];
    out[b * FOUT + h] = o;
  }
}

extern "C" void kernel_launch(void* const* d_in, const int* in_sizes, int n_in,
                              void* d_out, int out_size, void* d_ws, size_t ws_size,
                              hipStream_t stream) {
  const float* image    = (const float*)d_in[0];
  const float* question = (const float*)d_in[1];
  const float* Wg1      = (const float*)d_in[2];
  const float* bg1      = (const float*)d_in[3];
  const float* Wg2      = (const float*)d_in[4];
  const float* bg2      = (const float*)d_in[5];
  const float* Wf1      = (const float*)d_in[6];
  const float* bf1      = (const float*)d_in[7];
  const float* Wf2      = (const float*)d_in[8];
  const float* bf2      = (const float*)d_in[9];
  float* out = (float*)d_out;

  u16*   wsb  = (u16*)d_ws;
  u16*   Lqp  = wsb + LQ_U16;
  u16*   Rp   = wsb + R_U16;
  u16*   Bswz = wsb + BS_U16;
  float* Sp   = (float*)((char*)d_ws + S_BYTE);

  prep<<<2 * NB * NN + 256, 256, 0, stream>>>(image, question, Wg1, bg1, Wg2,
                                              Lqp, Rp, Sp, Bswz);
  pair_gemm<<<256, 512, 0, stream>>>(Lqp, Rp, Bswz, bg2, Sp);
  final_mlp<<<NB, 256, 0, stream>>>(Sp, Wf1, bf1, Wf2, bf2, out);
}

// Round 14
// 118.037 us; speedup vs baseline: 1.0272x; 1.0272x over previous
//
#include <hip/hip_runtime.h>
#include <hip/hip_bf16.h>

// Problem constants
#define NB   32      // batch
#define NC   24      // image channels
#define ND   12      // spatial
#define NN   144     // ND*ND objects
#define QD   11
#define GH   256
#define FOUT 10

typedef unsigned short u16;
typedef __attribute__((ext_vector_type(8))) short bf16x8;
typedef __attribute__((ext_vector_type(4))) float f32x4;
typedef __attribute__((ext_vector_type(16))) float f32x16;

// Workspace layout (u16 units unless noted):
//   Lqb  u16 [32][144][256]  off 0          (= L + q@Wg1_q + bg1, bf16)
//   Rb   u16 [32][144][256]  off 1179648
//   Bswz u16 [128][64][8]    off 2359296    (32x32x16 B-fragment order)
//   S    f32 [32][256]       byte-off 4849664
#define LQ_U16  0
#define R_U16   1179648
#define BS_U16  2359296
#define S_BYTE  4849664

__device__ inline float b2f(u16 v) {
  union { unsigned u; float f; } c; c.u = ((unsigned)v) << 16; return c.f;
}
__device__ inline u16 f2b(float f) {
  __hip_bfloat16 h = __float2bfloat16(f);
  return *reinterpret_cast<u16*>(&h);
}

// ---------------------------------------------------------------------------
// Fused prep:
//  blocks [0, 9216): per-object projections -> bf16 (Lq folds q-term + bg1).
//  blocks [9216, 9472): Wg2 -> bf16 B-fragment swizzle (32x32x16 frags):
//    frag f = ks*8 + nf; elem (l,e): k = ks*16 + (l>>5)*8 + e,
//    col = nf*32 + (l&31). Also zero S.
// ---------------------------------------------------------------------------
__global__ __launch_bounds__(256) void prep(const float* __restrict__ image,
                                            const float* __restrict__ question,
                                            const float* __restrict__ Wg1,
                                            const float* __restrict__ bg1,
                                            const float* __restrict__ Wg2,
                                            u16* __restrict__ Lq,
                                            u16* __restrict__ R,
                                            float* __restrict__ S,
                                            u16* __restrict__ Bswz) {
  int blk = blockIdx.x;
  int h   = threadIdx.x;
  if (blk < 2 * NB * NN) {
    int p     = blk % NN;
    int rest2 = blk / NN;
    int b     = rest2 & (NB - 1);
    int which = rest2 >> 5;
    const float* Wrow = Wg1 + which * (NC + 2) * GH;
    const float* img  = image + b * (NC * NN) + p;
    float acc = 0.f;
#pragma unroll
    for (int c = 0; c < NC; ++c) acc += img[c * NN] * Wrow[c * GH + h];
    int i = p / ND, j = p - i * ND;
    const float inv = 1.0f / (ND - 1);
    acc += (j * inv) * Wrow[24 * GH + h];
    acc += (i * inv) * Wrow[25 * GH + h];
    if (which == 0) {
      acc += bg1[h];
#pragma unroll
      for (int tq = 0; tq < QD; ++tq)
        acc += question[b * QD + tq] * Wg1[(2 * (NC + 2) + tq) * GH + h];
      Lq[(b * NN + p) * GH + h] = f2b(acc);
    } else {
      R[(b * NN + p) * GH + h] = f2b(acc);
    }
  } else {
    int tid = (blk - 2 * NB * NN) * 256 + h;   // 0..65535
    int e   = tid & 7;
    int l   = (tid >> 3) & 63;
    int f   = tid >> 9;                        // 0..127
    int ks  = f >> 3, nf = f & 7;
    int k = ks * 16 + ((l >> 5) << 3) + e;
    int n = (nf << 5) + (l & 31);
    Bswz[tid] = f2b(Wg2[k * GH + n]);
    if (tid < NB * GH) S[tid] = 0.f;
  }
}

// ---------------------------------------------------------------------------
// MFMA pair GEMM v14: 32x32x16 MFMA + B in PERSISTENT REGISTERS.
// Block = 512 thr (8 waves, wave-grid 2m x 4n), tile = 128 pairs x 256 cols.
// Wave owns 64 rows x 64 cols: acc[2][2] f32x16 = 64 regs; B-frags for its
// 64 cols x all K: bq[2][16] = 128 regs, loaded ONCE per block -> per-tile
// B L2-traffic is ZERO (was 256 KB/tile = the measured wall).
// A: 64 KB LDS, v12-proven phase split [build | bar | mma+epi | bar].
// XOR-swizzled A-frag store/read (8-lane bank sweep verified conflict-free).
// Grid = 256 blocks (1/CU) XCD-pinned; ~20 tiles/block.
// ---------------------------------------------------------------------------
__global__ __launch_bounds__(512, 1) void pair_gemm(const u16* __restrict__ Lq,
                                                    const u16* __restrict__ R,
                                                    const u16* __restrict__ Bswz,
                                                    const float* __restrict__ bg2,
                                                    float* __restrict__ S) {
  const int bid = blockIdx.x;          // 0..255
  const int xcd = bid & 7;
  const int idx = bid >> 3;            // 0..31
  const int b   = xcd * 4 + (idx >> 3);
  const int bi  = idx & 7;             // 8 blocks per batch, 162 tiles
  const int t0  = bi * 20 + (bi < 2 ? bi : 2);
  const int cnt = 20 + (bi < 2 ? 1 : 0);

  // A fragments: [ks 16][mf 4][lane 64][8 bf16] = 64 KB
  __shared__ __align__(16) u16 As[16 * 4 * 64 * 8];

  const int t = threadIdx.x;
  const int w = t >> 6, l = t & 63;
  const int wn = w & 3, wm = w >> 2;
  // builder role: row brow (0..127), k-octet class oc (0..3)
  const int brow = t >> 2;
  const int oc   = t & 3;

  const u16* Lbase = Lq + b * NN * GH;
  const u16* Rbase = R + b * NN * GH;
  const u16* Bl    = Bswz + l * 8;

  // ---- persistent B: wave wn's 64 cols, all 16 k-steps (128 VGPRs) ----
  bf16x8 bq[2][16];
#pragma unroll
  for (int j = 0; j < 2; ++j)
#pragma unroll
    for (int ks = 0; ks < 16; ++ks)
      bq[j][ks] = *(const bf16x8*)
          (Bl + ((size_t)((ks << 3) | (wn << 1) | j) << 9));

  float bgv[2];
#pragma unroll
  for (int j = 0; j < 2; ++j)
    bgv[j] = bg2[(wn << 6) + (j << 5) + (l & 31)];
  float ssum[2] = {0.f, 0.f};

  for (int tt = 0; tt < cnt; ++tt) {
    // ---- build phase: 128x256 A-tile into LDS fragment layout ----
    {
      int p = (t0 + tt) * 128 + brow;
      int i = p / NN, j = p - i * NN;
      const u16* Lr = Lbase + i * GH;
      const u16* Rr = Rbase + j * GH;
#pragma unroll
      for (int u = 0; u < 8; ++u) {
        const int ko = oc + (u << 2);        // k-octet 0..31
        bf16x8 lv = *(const bf16x8*)(Lr + ko * 8);
        bf16x8 rv = *(const bf16x8*)(Rr + ko * 8);
        u16 o[8];
#pragma unroll
        for (int e = 0; e < 8; ++e) {
          float v = b2f((u16)lv[e]) + b2f((u16)rv[e]);
          o[e] = f2b(v > 0.f ? v : 0.f);
        }
        const int ks = ko >> 1;              // k-step 0..15 (= 2u + (oc>>1))
        const int kb = ko & 1;               // k-half within step (= oc&1)
        const int mf = brow >> 5;            // 32-row frag 0..3
        const int pl = ((kb << 5) | (brow & 31)) ^ (oc << 1);  // swizzled lane
        *(bf16x8*)&As[((((ks << 2) | mf) << 6) | pl) << 3] = *(bf16x8*)o;
      }
    }
    __syncthreads();

    // ---- MFMA phase: 16 ks x {2 ds_read A, 4 MFMA 32x32x16} ----
    f32x16 acc[2][2] = {};
#pragma unroll
    for (int ks = 0; ks < 16; ++ks) {
      bf16x8 af[2];
#pragma unroll
      for (int i = 0; i < 2; ++i) {
        const int mf = (wm << 1) | i;
        const int g  = ((((ks & 1) << 1) | (l >> 5)) << 1);
        af[i] = *(const bf16x8*)&As[((((ks << 2) | mf) << 6) | (l ^ g)) << 3];
      }
      __builtin_amdgcn_s_setprio(1);
#pragma unroll
      for (int i = 0; i < 2; ++i)
#pragma unroll
        for (int j = 0; j < 2; ++j)
          acc[i][j] = __builtin_amdgcn_mfma_f32_32x32x16_bf16(
              af[i], bq[j][ks], acc[i][j], 0, 0, 0);
      __builtin_amdgcn_s_setprio(0);
    }

    // epilogue: fold relu(acc + bg2) into running sums
#pragma unroll
    for (int j = 0; j < 2; ++j) {
      float s = 0.f;
#pragma unroll
      for (int i = 0; i < 2; ++i)
#pragma unroll
        for (int r = 0; r < 16; ++r) {
          float v = acc[i][j][r] + bgv[j];
          s += v > 0.f ? v : 0.f;
        }
      ssum[j] += s;
    }
    __syncthreads();
  }

  // Final reduce: 32x32 C/D col = l&31; lanes l, l+32 cover disjoint rows of
  // the same col -> one shfl; lanes 0..31 atomically add 2 cols each.
  float* Sb = S + b * GH;
#pragma unroll
  for (int j = 0; j < 2; ++j) {
    float s = ssum[j];
    s += __shfl_xor(s, 32, 64);
    if (l < 32) atomicAdd(&Sb[(wn << 6) + (j << 5) + l], s);
  }
}

// ---------------------------------------------------------------------------
// Final f-MLP: out = relu(S@Wf1+bf1)@Wf2+bf2. One block per batch.
// ---------------------------------------------------------------------------
__global__ __launch_bounds__(256) void final_mlp(const float* __restrict__ S,
                                                 const float* __restrict__ Wf1,
                                                 const float* __restrict__ bf1,
                                                 const float* __restrict__ Wf2,
                                                 const float* __restrict__ bf2,
                                                 float* __restrict__ out) {
  __shared__ float sS[GH];
  __shared__ float oS[GH];
  int b = blockIdx.x, h = threadIdx.x;
  sS[h] = S[b * GH + h];
  __syncthreads();
  float acc = bf1[h];
#pragma unroll 8
  for (int k = 0; k < GH; ++k) acc += sS[k] * Wf1[k * GH + h];
  oS[h] = acc > 0.f ? acc : 0.f;
  __syncthreads();
  if (h < FOUT) {
    float o = bf2[h];
#pragma unroll 8
    for (int k = 0; k < GH; ++k) o += oS[k] * Wf2[k * FOUT + h];
    out[b * FOUT + h] = o;
  }
}

extern "C" void kernel_launch(void* const* d_in, const int* in_sizes, int n_in,
                              void* d_out, int out_size, void* d_ws, size_t ws_size,
                              hipStream_t stream) {
  const float* image    = (const float*)d_in[0];
  const float* question = (const float*)d_in[1];
  const float* Wg1      = (const float*)d_in[2];
  const float* bg1      = (const float*)d_in[3];
  const float* Wg2      = (const float*)d_in[4];
  const float* bg2      = (const float*)d_in[5];
  const float* Wf1      = (const float*)d_in[6];
  const float* bf1      = (const float*)d_in[7];
  const float* Wf2      = (const float*)d_in[8];
  const float* bf2      = (const float*)d_in[9];
  float* out = (float*)d_out;

  u16*   wsb  = (u16*)d_ws;
  u16*   Lqp  = wsb + LQ_U16;
  u16*   Rp   = wsb + R_U16;
  u16*   Bswz = wsb + BS_U16;
  float* Sp   = (float*)((char*)d_ws + S_BYTE);

  prep<<<2 * NB * NN + 256, 256, 0, stream>>>(image, question, Wg1, bg1, Wg2,
                                              Lqp, Rp, Sp, Bswz);
  pair_gemm<<<256, 512, 0, stream>>>(Lqp, Rp, Bswz, bg2, Sp);
  final_mlp<<<NB, 256, 0, stream>>>(Sp, Wf1, bf1, Wf2, bf2, out);
}